// Round 10
// baseline (445.844 us; speedup 1.0000x reference)
//
#include <hip/hip_runtime.h>
#include <hip/hip_bf16.h>

#define N 8192
#define IND 128
#define OUTD 128
#define JC 16
#define JLEN 512    /* N/JC */
#define SUBC 4      /* 128-j sub-chunks per block */
#define TSUB 4      /* 32-j steps per sub-chunk */

typedef float f32x4 __attribute__((ext_vector_type(4)));
typedef short s16x8 __attribute__((ext_vector_type(8)));
typedef _Float16 f16;
typedef _Float16 f16x2 __attribute__((ext_vector_type(2)));
typedef _Float16 f16x4 __attribute__((ext_vector_type(4)));
typedef unsigned int u32x4 __attribute__((ext_vector_type(4)));

static __device__ inline unsigned short f2bf(float f) {
    union { float f; unsigned u; } v; v.f = f;
    unsigned u = v.u + 0x7fffu + ((v.u >> 16) & 1u);
    return (unsigned short)(u >> 16);
}
static __device__ inline float bf2f(unsigned short b) {
    union { unsigned u; float f; } v; v.u = ((unsigned)b) << 16;
    return v.f;
}
static __device__ __forceinline__ unsigned pkbf(float a, float b) {
    __hip_bfloat162 t = __float22bfloat162_rn(make_float2(a, b));
    unsigned u;
    __builtin_memcpy(&u, &t, 4);
    return u;
}
static __device__ __forceinline__ void async16(const void* g, void* l) {
    __builtin_amdgcn_global_load_lds(
        (const __attribute__((address_space(1))) unsigned int*)g,
        (__attribute__((address_space(3))) unsigned int*)l, 16, 0, 0);
}
// select v[quad] without scratch (3 cndmask)
static __device__ __forceinline__ unsigned qsel(u32x4 v, int quad) {
    unsigned a = (quad & 1) ? v[1] : v[0];
    unsigned b = (quad & 1) ? v[3] : v[2];
    return (quad & 2) ? b : a;
}

// ---------------------------------------------------------------------------
// Kernel 0: adj (268 MB) -> stride-4 bitmask words (8 MB), float4 streaming.
// Per 128-j block b, 4 uint32 words M_q at [row*256 + 4b + q]:
//   M_q byte t, bit i  <->  adj[row][128b + 32t + 4i + q]
// ---------------------------------------------------------------------------
__global__ __launch_bounds__(256) void k0_pack(const float* __restrict__ adj,
                                               unsigned int* __restrict__ bits32) {
    const int row = blockIdx.x;
    const int wave = threadIdx.x >> 6, lane = threadIdx.x & 63;
    const float4* src = (const float4*)(adj + (size_t)row * N + wave * 2048);
    unsigned acc = 0;
#pragma unroll
    for (int it = 0; it < 8; ++it) {
        float4 v = src[it * 64 + lane];
        unsigned long long b0 = __ballot(v.x != 0.0f);
        unsigned long long b1 = __ballot(v.y != 0.0f);
        unsigned long long b2 = __ballot(v.z != 0.0f);
        unsigned long long b3 = __ballot(v.w != 0.0f);
        unsigned w[8];
        w[0] = (unsigned)b0; w[1] = (unsigned)b1;
        w[2] = (unsigned)b2; w[3] = (unsigned)b3;
        w[4] = (unsigned)(b0 >> 32); w[5] = (unsigned)(b1 >> 32);
        w[6] = (unsigned)(b2 >> 32); w[7] = (unsigned)(b3 >> 32);
#pragma unroll
        for (int z = 0; z < 8; ++z)
            acc = (lane == it * 8 + z) ? w[z] : acc;
    }
    bits32[(size_t)row * 256 + wave * 64 + lane] = acc;
}

// ---------------------------------------------------------------------------
// Kernel 1: h = x @ W -> hTp[c][slot] (permuted j/node axis, 128 x N bf16).
// slot(n) = (n&~31) | ((n&3)<<3) | ((n&31)>>2). Tile rows assigned transposed
// (sigma(rho) = T + 4*(rho&3) + (rho>>2)) so the C-write stays ushort4-dense.
// ---------------------------------------------------------------------------
__global__ __launch_bounds__(256) void k1_xw(const float* __restrict__ x,
                                             const float* __restrict__ W,
                                             unsigned short* __restrict__ hTp) {
    __shared__ unsigned short Wl[128 * 130];
    const int tid = threadIdx.x;
    {
        int k = tid >> 1, n0 = (tid & 1) * 64;
        const float4* src = (const float4*)(W + k * 128 + n0);
#pragma unroll
        for (int v = 0; v < 16; ++v) {
            float4 f = src[v];
            int base = k * 130 + n0 + v * 4;
            Wl[base + 0] = f2bf(f.x);
            Wl[base + 1] = f2bf(f.y);
            Wl[base + 2] = f2bf(f.z);
            Wl[base + 3] = f2bf(f.w);
        }
    }
    __syncthreads();
    const int wave = tid >> 6, lane = tid & 63;
    const int m = lane & 15, quad = lane >> 4;
    const int T = blockIdx.x * 64 + wave * 16;
    const int arow = T + 4 * (m & 3) + (m >> 2);   // sigma(m)

    f32x4 acc[8];
#pragma unroll
    for (int t = 0; t < 8; ++t) acc[t] = (f32x4){0.f, 0.f, 0.f, 0.f};

#pragma unroll
    for (int ks = 0; ks < 4; ++ks) {
        const int k0 = ks * 32 + quad * 8;
        const float4* xp = (const float4*)(x + (size_t)arow * 128 + k0);
        float4 xa = xp[0], xb = xp[1];
        s16x8 afrag;
        afrag[0] = (short)f2bf(xa.x); afrag[1] = (short)f2bf(xa.y);
        afrag[2] = (short)f2bf(xa.z); afrag[3] = (short)f2bf(xa.w);
        afrag[4] = (short)f2bf(xb.x); afrag[5] = (short)f2bf(xb.y);
        afrag[6] = (short)f2bf(xb.z); afrag[7] = (short)f2bf(xb.w);
#pragma unroll
        for (int nt = 0; nt < 8; ++nt) {
            const int n = nt * 16 + m;
            s16x8 bfrag;
#pragma unroll
            for (int j = 0; j < 8; ++j)
                bfrag[j] = (short)Wl[(k0 + j) * 130 + n];
            acc[nt] = __builtin_amdgcn_mfma_f32_16x16x32_bf16(afrag, bfrag, acc[nt], 0, 0, 0);
        }
    }
    // store: slot base for (quad, r=0..3) is contiguous
    const int sbase = blockIdx.x * 64 + (wave & 2) * 16 + quad * 8 + (wave & 1) * 4;
#pragma unroll
    for (int nt = 0; nt < 8; ++nt) {
        const int c = nt * 16 + m;
        ushort4 pk;
        pk.x = f2bf(acc[nt][0]); pk.y = f2bf(acc[nt][1]);
        pk.z = f2bf(acc[nt][2]); pk.w = f2bf(acc[nt][3]);
        *(ushort4*)(hTp + (size_t)c * N + sbase) = pk;
    }
}

// ---------------------------------------------------------------------------
// Kernel 2: per-node separable arrays. Thread owns SLOT s (coalesced hTp
// reads); node n = invperm(s). As/Cs node-indexed; BDp slot-indexed.
// ---------------------------------------------------------------------------
__global__ __launch_bounds__(256) void k2_e(const unsigned short* __restrict__ hTp,
                                            const float* __restrict__ a_src,
                                            const float* __restrict__ a_dst,
                                            float* __restrict__ As, float* __restrict__ Cs,
                                            uint2* __restrict__ BDp) {
    const int s = blockIdx.x * 256 + threadIdx.x;
    const int n = (s & ~31) | ((s & 7) << 2) | ((s >> 3) & 3);
    float es0 = 0.f, ed0 = 0.f, es1 = 0.f, ed1 = 0.f;
#pragma unroll 8
    for (int c = 0; c < 128; ++c) {
        float v = bf2f(hTp[(size_t)c * N + s]);
        float as = a_src[c], ad = a_dst[c];
        if (c < 64) { es0 += v * as; ed0 += v * ad; }
        else        { es1 += v * as; ed1 += v * ad; }
    }
    As[n]     = __expf(es0);
    As[N + n] = __expf(es1);
    Cs[n]     = __expf(0.2f * es0);
    Cs[N + n] = __expf(0.2f * es1);
    uint2 bd;
    bd.x = pkbf(__expf(ed0), __expf(0.2f * ed0));
    bd.y = pkbf(__expf(ed1), __expf(0.2f * ed1));
    BDp[s] = bd;
}

// ---------------------------------------------------------------------------
// Kernel 3 (main): 128 i x 512 j per block; each wave computes TWO 16-row
// tiles from the SAME staged hT/BD -> 2x MFMA per LDS read, half the
// wave-steps and barriers of R9. Pure-LDS compute between barriers.
// grid = (64 i-tiles, 16 j-chunks); block = 256 thr = 4 waves.
// ---------------------------------------------------------------------------
__global__ __launch_bounds__(256, 3) void k3_main(const unsigned int* __restrict__ bits32,
                                                  const unsigned short* __restrict__ hTp,
                                                  const float* __restrict__ As,
                                                  const float* __restrict__ Cs,
                                                  const uint2* __restrict__ BDp,
                                                  f16* __restrict__ Up,
                                                  float* __restrict__ Lp) {
    __shared__ float4 smem4[2112];                       // 33792 B
    unsigned short* hTl = (unsigned short*)smem4;        // 32 KB
    uint2* bdl = (uint2*)((char*)smem4 + 32768);         // 1 KB
    const int tid = threadIdx.x;
    const int wave = tid >> 6, lane = tid & 63;
    const int m = lane & 15, quad = lane >> 4;
    const int ibase = blockIdx.x * 128 + wave * 32;
    const int ra = ibase + m, rb = ibase + 16 + m;
    const int jc = blockIdx.y;
    const int j0 = jc * JLEN;

    const float A0a = As[ra], C0a = Cs[ra], A1a = As[N + ra], C1a = Cs[N + ra];
    const float A0b = As[rb], C0b = Cs[rb], A1b = As[N + rb], C1b = Cs[N + rb];

    f32x4 acc[2][2][4];   // [rowgroup][head][nt]
#pragma unroll
    for (int g = 0; g < 2; ++g)
#pragma unroll
        for (int h = 0; h < 2; ++h)
#pragma unroll
            for (int nt = 0; nt < 4; ++nt) acc[g][h][nt] = (f32x4){0.f, 0.f, 0.f, 0.f};
    f32x4 accS[2][2];
    accS[0][0] = accS[0][1] = accS[1][0] = accS[1][1] = (f32x4){0.f, 0.f, 0.f, 0.f};

    s16x8 ones;
#pragma unroll
    for (int t = 0; t < 8; ++t) ones[t] = (short)0x3F80;

    const int crow = lane >> 4;
    const int gd = lane & 15;

#pragma unroll 1
    for (int sc = 0; sc < SUBC; ++sc) {
        const int jb = j0 + sc * 128;
        if (sc) __syncthreads();
        u32x4 mka = *(const u32x4*)(bits32 + (size_t)ra * 256 + (jb >> 5));
        u32x4 mkb = *(const u32x4*)(bits32 + (size_t)rb * 256 + (jb >> 5));
        if (wave == 0)
            async16(BDp + jb + lane * 2, bdl);
#pragma unroll
        for (int rr = 0; rr < 8; ++rr) {
            const int rg = wave * 8 + rr;
            const int c = rg * 4 + crow;
            const int gs = gd ^ (c & 7);
            async16(hTp + (size_t)c * N + jb + gs * 8, hTl + rg * 512);
        }
        __syncthreads();

        const unsigned wa = qsel(mka, quad);
        const unsigned wb = qsel(mkb, quad);

#pragma unroll
        for (int t = 0; t < TSUB; ++t) {
            u32x4 bq[4];
            const u32x4* bp = (const u32x4*)(bdl + (t * 32 + quad * 8));
#pragma unroll
            for (int z = 0; z < 4; ++z) bq[z] = bp[z];
            const unsigned mba = (wa >> (t * 8)) & 0xffu;
            const unsigned mbb = (wb >> (t * 8)) & 0xffu;

            float pa0[8], pa1[8], pb0[8], pb1[8];
#pragma unroll
            for (int jj = 0; jj < 8; ++jj) {
                const unsigned u0 = bq[jj >> 1][(jj & 1) * 2];
                const unsigned u1 = bq[jj >> 1][(jj & 1) * 2 + 1];
                float B0 = __uint_as_float(u0 << 16);
                float D0 = __uint_as_float(u0 & 0xffff0000u);
                float B1 = __uint_as_float(u1 << 16);
                float D1 = __uint_as_float(u1 & 0xffff0000u);
                bool oa = (mba >> jj) & 1u;
                bool ob = (mbb >> jj) & 1u;
                pa0[jj] = oa ? fmaxf(A0a * B0, C0a * D0) : 0.0f;
                pa1[jj] = oa ? fmaxf(A1a * B1, C1a * D1) : 0.0f;
                pb0[jj] = ob ? fmaxf(A0b * B0, C0b * D0) : 0.0f;
                pb1[jj] = ob ? fmaxf(A1b * B1, C1b * D1) : 0.0f;
            }
            unsigned qa0[4], qa1[4], qb0[4], qb1[4];
#pragma unroll
            for (int q = 0; q < 4; ++q) {
                qa0[q] = pkbf(pa0[q * 2], pa0[q * 2 + 1]);
                qa1[q] = pkbf(pa1[q * 2], pa1[q * 2 + 1]);
                qb0[q] = pkbf(pb0[q * 2], pb0[q * 2 + 1]);
                qb1[q] = pkbf(pb1[q * 2], pb1[q * 2 + 1]);
            }
            s16x8 p0a, p1a, p0b, p1b;
            __builtin_memcpy(&p0a, qa0, 16);
            __builtin_memcpy(&p1a, qa1, 16);
            __builtin_memcpy(&p0b, qb0, 16);
            __builtin_memcpy(&p1b, qb1, 16);

#pragma unroll
            for (int nt = 0; nt < 4; ++nt) {
                const int c0 = nt * 16 + m;
                const int go = ((t * 4 + quad) ^ (c0 & 7)) * 8;
                s16x8 h0 = *(const s16x8*)(hTl + c0 * 128 + go);
                s16x8 h1 = *(const s16x8*)(hTl + (c0 + 64) * 128 + go);
                acc[0][0][nt] = __builtin_amdgcn_mfma_f32_16x16x32_bf16(p0a, h0, acc[0][0][nt], 0, 0, 0);
                acc[1][0][nt] = __builtin_amdgcn_mfma_f32_16x16x32_bf16(p0b, h0, acc[1][0][nt], 0, 0, 0);
                acc[0][1][nt] = __builtin_amdgcn_mfma_f32_16x16x32_bf16(p1a, h1, acc[0][1][nt], 0, 0, 0);
                acc[1][1][nt] = __builtin_amdgcn_mfma_f32_16x16x32_bf16(p1b, h1, acc[1][1][nt], 0, 0, 0);
            }
            accS[0][0] = __builtin_amdgcn_mfma_f32_16x16x32_bf16(p0a, ones, accS[0][0], 0, 0, 0);
            accS[0][1] = __builtin_amdgcn_mfma_f32_16x16x32_bf16(p1a, ones, accS[0][1], 0, 0, 0);
            accS[1][0] = __builtin_amdgcn_mfma_f32_16x16x32_bf16(p0b, ones, accS[1][0], 0, 0, 0);
            accS[1][1] = __builtin_amdgcn_mfma_f32_16x16x32_bf16(p1b, ones, accS[1][1], 0, 0, 0);
        }
    }

    // ---- epilogue: per-rowgroup LDS transpose (wave-local), coalesced stores
    __syncthreads();
    float* smf = (float*)smem4 + wave * (16 * 129);
    f16* Ub = Up + (size_t)jc * N * 128;
#pragma unroll
    for (int g = 0; g < 2; ++g) {
#pragma unroll
        for (int h = 0; h < 2; ++h)
#pragma unroll
            for (int nt = 0; nt < 4; ++nt) {
                const int c = h * 64 + nt * 16 + m;
#pragma unroll
                for (int r = 0; r < 4; ++r)
                    smf[(quad * 4 + r) * 129 + c] = acc[g][h][nt][r];
            }
        // same-wave ds_write -> ds_read: DS pipe in-order per wave
#pragma unroll
        for (int r16 = 0; r16 < 16; ++r16) {
            float v0 = smf[r16 * 129 + lane * 2];
            float v1 = smf[r16 * 129 + lane * 2 + 1];
            f16x2 pk; pk[0] = (f16)v0; pk[1] = (f16)v1;
            *(f16x2*)(Ub + (size_t)(ibase + g * 16 + r16) * 128 + lane * 2) = pk;
        }
        if (m == 0) {
#pragma unroll
            for (int h = 0; h < 2; ++h)
#pragma unroll
                for (int r = 0; r < 4; ++r)
                    Lp[((size_t)jc * 2 + h) * N + ibase + g * 16 + quad * 4 + r] = accS[g][h][r];
        }
    }
}

// ---------------------------------------------------------------------------
// Kernel 4: sum fp16 partials over 16 j-chunks, divide by row-sum.
// ---------------------------------------------------------------------------
__global__ __launch_bounds__(256) void k4_reduce(const f16* __restrict__ Up,
                                                 const float* __restrict__ Lp,
                                                 float* __restrict__ out) {
    const int base = (blockIdx.x * 256 + threadIdx.x) * 4;
    const int i = base >> 7, c = base & 127, h = c >> 6;
    float su0 = 0.f, su1 = 0.f, su2 = 0.f, su3 = 0.f, sl = 0.f;
#pragma unroll
    for (int jcc = 0; jcc < JC; ++jcc) {
        f16x4 u = *(const f16x4*)(Up + (size_t)jcc * N * 128 + base);
        su0 += (float)u[0]; su1 += (float)u[1];
        su2 += (float)u[2]; su3 += (float)u[3];
        sl += Lp[((size_t)jcc * 2 + h) * N + i];
    }
    float inv = 1.0f / sl;
    float4 o; o.x = su0 * inv; o.y = su1 * inv; o.z = su2 * inv; o.w = su3 * inv;
    *(float4*)(out + base) = o;
}

extern "C" void kernel_launch(void* const* d_in, const int* in_sizes, int n_in,
                              void* d_out, int out_size, void* d_ws, size_t ws_size,
                              hipStream_t stream) {
    const float* x     = (const float*)d_in[0];
    const float* adj   = (const float*)d_in[1];
    const float* W     = (const float*)d_in[2];
    const float* a_src = (const float*)d_in[3];
    const float* a_dst = (const float*)d_in[4];
    float* out = (float*)d_out;
    char* ws = (char*)d_ws;

    size_t off = 0;
    unsigned short* hTp = (unsigned short*)(ws + off); off += (size_t)128 * N * 2;
    float* As = (float*)(ws + off); off += (size_t)2 * N * 4;
    float* Cs = (float*)(ws + off); off += (size_t)2 * N * 4;
    uint2* BDp = (uint2*)(ws + off); off += (size_t)N * 8;
    unsigned int* bits32 = (unsigned int*)(ws + off); off += (size_t)N * 256 * 4;
    f16* Up = (f16*)(ws + off); off += (size_t)JC * N * 128 * 2;
    float* Lp = (float*)(ws + off); off += (size_t)JC * 2 * N * 4;

    k0_pack<<<N, 256, 0, stream>>>(adj, bits32);
    k1_xw<<<N / 64, 256, 0, stream>>>(x, W, hTp);
    k2_e<<<N / 256, 256, 0, stream>>>(hTp, a_src, a_dst, As, Cs, BDp);
    dim3 g3(N / 128, JC);
    k3_main<<<g3, 256, 0, stream>>>(bits32, hTp, As, Cs, BDp, Up, Lp);
    k4_reduce<<<(N * 128) / (256 * 4), 256, 0, stream>>>(Up, Lp, out);
}